// Round 3
// baseline (5044.996 us; speedup 1.0000x reference)
//
#include <hip/hip_runtime.h>
#include <cstdint>
#include <cstddef>

#define BATCH   4096
#define IN_DIM  1024
#define HID     16384
#define KSEL    32

// ---------------------------------------------------------------------------
// Kernel 1: encoder GEMM  C[B,H] = X[B,D] @ W_enc[H,D]^T + b_enc
// fp32, 128x128 tile, BK=32, 256 threads, 8x8 micro-tile, 4 blocks/CU.
// A (X) read DIRECTLY from global (L1-resident), only B (W_enc) staged in LDS.
//
// NUMERICS CONTRACT (do not change): per output element, fmaf over k in
// strictly ascending order with a single accumulator, then + bias. Top-k
// rank-32 boundary gaps are ~0.007; any reordering (MFMA bf16x3: absmax
// 4.31, or k-splitting) flips selections vs the np reference. MFMA unusable.
//
// r6 POST-MORTEM (this structure at 1830us): LDS-read-pipe-bound.
//   FMA floor 874us; LDS demand was 1.0 B/FMA = 128 B/cyc/CU vs ~85 B/cyc
//   ds_read_b128 throughput -> ~1320us LDS occupancy + 12% bank-conflict tax
//   (1.34e8 cyc) + barrier bubbles = 1830us. Bigger micro-tiles to cut
//   B/FMA hit the register wall (r5: acc[16][8] spilled, REGRESSED).
//
// r7 FIX: A off the LDS pipe. Consecutive blocks share bm (bn is fast grid
// dim) -> the 4 co-resident blocks read the SAME 16KB A-slice per k0 ->
// L1-resident. Within a wave the a4 address depends only on ty -> 4 unique
// 16B segments per load instr -> coalesced L1 broadcast. LDS demand halves
// to 0.5 B/FMA (64 B/cyc < 85 ceiling): FMA issue becomes the limiter.
//
// Register discipline (r1/r2/r3/r5 lessons): acc 64 + b4 32 + a4 + addr
// ~= 120 VGPR, fits the 128 cap of launch_bounds(256,4) without spill.
// A-addressing: per-thread base xr (ty rows), i*IN_DIM and kq*4 fold into
// immediates/SGPR adds. Keep staging register-free (global_load_lds).
//
// Staging (B only): global_load_lds width=16 into ROW-MAJOR LDS, 16B chunks
// XOR-swizzled by ((row>>3)&7) so compute ds_read_b128 is conflict-free
// (16 tx rows over 8 4-bank groups = 2-way aliasing, ~free per m136).
// ---------------------------------------------------------------------------
#define BKK 32

__global__ __launch_bounds__(256, 4)
void enc_gemm(const float* __restrict__ X, const float* __restrict__ W,
              const float* __restrict__ bias, float* __restrict__ C)
{
    __shared__ __align__(16) float Bs[128 * BKK];   // 16 KB, row-major, swizzled

    const int bn = blockIdx.x;   // HID/128 = 128 (fast dim: co-resident blocks share bm)
    const int bm = blockIdx.y;   // BATCH/128 = 32
    const int t  = threadIdx.x;
    const int tx = t & 15;       // 8 cols each
    const int ty = t >> 4;       // 8 rows each

    float acc[8][8];
#pragma unroll
    for (int i = 0; i < 8; ++i)
#pragma unroll
        for (int j = 0; j < 8; ++j) acc[i][j] = 0.f;

    const float* Wb = W + (size_t)(bn * 128) * IN_DIM;
    // this thread's 8 A-rows (read straight from global; L1-resident slice)
    const float* xr = X + (size_t)(bm * 128 + ty * 8) * IN_DIM;

    const int bswz = tx & 7;     // B-read swizzle key ((n>>3)&7 = tx&7)

    for (int k0 = 0; k0 < IN_DIM; k0 += BKK) {
        // ---- stage 128x32 B tile: 4 x 16B per thread.
        // LDS slot s holds row m = s>>3, global 16B-chunk (s&7)^((m>>3)&7).
        // Lane-contiguous LDS dst (s*16B) satisfies the global_load_lds
        // wave-uniform-base + lane*16 rule.
#pragma unroll
        for (int q = 0; q < 4; ++q) {
            const int s  = q * 256 + t;           // 0..1023
            const int m  = s >> 3;                // 0..127
            const int gc = (s & 7) ^ ((m >> 3) & 7);
            __builtin_amdgcn_global_load_lds(
                (const __attribute__((address_space(1))) void*)(Wb + (size_t)m * IN_DIM + k0 + gc * 4),
                (__attribute__((address_space(3))) void*)(Bs + s * 4), 16, 0, 0);
        }
        __syncthreads();   // drains vmcnt (global_load_lds) before reads

        // ---- compute: 8 groups of 4 consecutive k, components in order.
        // b4[8] from LDS; a4 from global (L1 broadcast, 4 unique addr/wave).
#pragma unroll
        for (int kq = 0; kq < 8; ++kq) {
            float4 b4[8];
#pragma unroll
            for (int j = 0; j < 8; ++j)
                b4[j] = *(const float4*)(Bs + (tx * 8 + j) * BKK + ((kq ^ bswz) * 4));
#pragma unroll
            for (int i = 0; i < 8; ++i) {
                const float4 a4 = *(const float4*)(xr + (size_t)i * IN_DIM + k0 + kq * 4);
                // k ascending per output: c = 0,1,2,3 (bit-identical chain)
#pragma unroll
                for (int j = 0; j < 8; ++j) acc[i][j] = fmaf(a4.x, b4[j].x, acc[i][j]);
#pragma unroll
                for (int j = 0; j < 8; ++j) acc[i][j] = fmaf(a4.y, b4[j].y, acc[i][j]);
#pragma unroll
                for (int j = 0; j < 8; ++j) acc[i][j] = fmaf(a4.z, b4[j].z, acc[i][j]);
#pragma unroll
                for (int j = 0; j < 8; ++j) acc[i][j] = fmaf(a4.w, b4[j].w, acc[i][j]);
            }
        }
        __syncthreads();
    }

    const int col0 = bn * 128 + tx * 8;
    float bv[8];
#pragma unroll
    for (int j = 0; j < 8; ++j) bv[j] = bias[col0 + j];
#pragma unroll
    for (int i = 0; i < 8; ++i) {
        const size_t rowoff = (size_t)(bm * 128 + ty * 8 + i) * HID + col0;
        float4 o0, o1;
        o0.x = acc[i][0] + bv[0]; o0.y = acc[i][1] + bv[1];
        o0.z = acc[i][2] + bv[2]; o0.w = acc[i][3] + bv[3];
        o1.x = acc[i][4] + bv[4]; o1.y = acc[i][5] + bv[5];
        o1.z = acc[i][6] + bv[6]; o1.w = acc[i][7] + bv[7];
        *(float4*)(C + rowoff)     = o0;
        *(float4*)(C + rowoff + 4) = o1;
    }
}

// ---------------------------------------------------------------------------
// Kernel 2 (v4): per-row exact top-32 by |value|, 4-level radix select on
// abs bit pattern. Row cached in LDS (64 KB) -> global traffic = 1 read +
// 1 write. Suffix "scan" via wave shuffles (no LDS scan array / barriers).
// Levels: bits 30:23 (256), 22:15 (256), 14:7 (256), 6:0 (128).
// ---------------------------------------------------------------------------
__global__ __launch_bounds__(256)
void topk_rows(float* __restrict__ E, int* __restrict__ idx_out,
               float* __restrict__ val_out)
{
    const int row = blockIdx.x;
    float* p = E + (size_t)row * HID;
    const int t    = threadIdx.x;
    const int lane = t & 63;
    const int wid  = t >> 6;

    __shared__ __align__(16) float row_s[HID];   // 64 KB row cache
    __shared__ unsigned h8[8][257];              // lvl-0 privatized hists
    __shared__ unsigned hist[256];
    __shared__ unsigned wsum[4];
    __shared__ unsigned s_prefix;
    __shared__ int s_rank, s_eq, s_cnt;

    // async-load the whole row into LDS (lane-contiguous 16B chunks)
#pragma unroll
    for (int c = 0; c < 16; ++c) {
        const int s = c * 256 + t;
        __builtin_amdgcn_global_load_lds(
            (const __attribute__((address_space(1))) void*)(p + (size_t)s * 4),
            (__attribute__((address_space(3))) void*)(row_s + s * 4), 16, 0, 0);
    }
    for (int i = t; i < 8 * 257; i += 256) ((unsigned*)h8)[i] = 0u;
    if (t == 0) { s_rank = KSEL; s_prefix = 0u; s_eq = 0; s_cnt = 0; }
    __syncthreads();

    // ---- level 0: exponent-byte histogram into 8 privatized copies
    unsigned* myh = h8[t & 7];
#pragma unroll
    for (int c = 0; c < 16; ++c) {
        const float4 v = *(const float4*)(row_s + (c * 256 + t) * 4);
        const float vv[4] = {v.x, v.y, v.z, v.w};
#pragma unroll
        for (int j = 0; j < 4; ++j)
            atomicAdd(&myh[(__float_as_uint(vv[j]) & 0x7FFFFFFFu) >> 23], 1u);
    }
    __syncthreads();

    const int psh_arr[4]  = {31, 23, 15, 7};
    const int sh_arr[4]   = {23, 15, 7, 0};
    const unsigned msk[4] = {255u, 255u, 255u, 127u};
    const int bits_arr[4] = {8, 8, 8, 7};

#pragma unroll
    for (int lvl = 0; lvl < 4; ++lvl) {
        const int r = s_rank;
        const unsigned pfx = s_prefix;

        unsigned mycnt;
        if (lvl == 0) {
            unsigned m = 0;
#pragma unroll
            for (int c = 0; c < 8; ++c) m += h8[c][t];
            mycnt = m;                       // own bin, no barrier needed
        } else {
            hist[t] = 0u;
            __syncthreads();
            const int psh = psh_arr[lvl];
            const int sh  = sh_arr[lvl];
#pragma unroll
            for (int c = 0; c < 16; ++c) {
                const float4 v = *(const float4*)(row_s + (c * 256 + t) * 4);
                const float vv[4] = {v.x, v.y, v.z, v.w};
#pragma unroll
                for (int j = 0; j < 4; ++j) {
                    const unsigned k = __float_as_uint(vv[j]) & 0x7FFFFFFFu;
                    if ((k >> psh) == pfx)   // few matches: contention trivial
                        atomicAdd(&hist[(k >> sh) & msk[lvl]], 1u);
                }
            }
            __syncthreads();
            mycnt = hist[t];
        }

        // wave-level inclusive suffix scan of bin counts (bin index = t)
        unsigned sv = mycnt;
#pragma unroll
        for (int off = 1; off < 64; off <<= 1) {
            const unsigned u = __shfl_down(sv, off, 64);
            sv += (lane + off < 64) ? u : 0u;
        }
        if (lane == 0) wsum[wid] = sv;       // this wave's 64-bin total
        __syncthreads();
        unsigned above = 0;
        for (int ww = wid + 1; ww < 4; ++ww) above += wsum[ww];
        const unsigned suff  = sv + above;   // sum of bins >= t
        const unsigned suffn = suff - mycnt; // sum of bins >  t
        if (suff >= (unsigned)r && suffn < (unsigned)r) {  // exactly one thread
            s_rank   = r - (int)suffn;
            s_prefix = (pfx << bits_arr[lvl]) | (unsigned)t;
        }
        __syncthreads();
    }

    const unsigned vkey = s_prefix;   // exact 31-bit abs key of the 32nd largest
    const int eq_need   = s_rank;     // how many ==vkey elements to keep (>=1)

    // ---- final: mask from LDS, write global row + compact (idx,val) lists
#pragma unroll
    for (int c = 0; c < 16; ++c) {
        const int i0 = (c * 256 + t) * 4;
        const float4 v = *(const float4*)(row_s + i0);
        float vv[4] = {v.x, v.y, v.z, v.w};
#pragma unroll
        for (int j = 0; j < 4; ++j) {
            const unsigned k = __float_as_uint(vv[j]) & 0x7FFFFFFFu;
            bool keep = false;
            if (k > vkey) keep = true;
            else if (k == vkey) {
                const int slot = atomicAdd(&s_eq, 1);
                if (slot < eq_need) keep = true;
            }
            if (keep) {
                const int ls = atomicAdd(&s_cnt, 1);
                idx_out[row * KSEL + ls] = i0 + j;
                val_out[row * KSEL + ls] = vv[j];
            } else {
                vv[j] = 0.f;
            }
        }
        float4 o; o.x = vv[0]; o.y = vv[1]; o.z = vv[2]; o.w = vv[3];
        *(float4*)(p + i0) = o;
    }
}

// ---------------------------------------------------------------------------
// Kernel 3: transpose W_dec [1024,16384] -> WdT [16384,1024] (ws scratch)
// ---------------------------------------------------------------------------
__global__ __launch_bounds__(256)
void transpose_wdec(const float* __restrict__ Wd, float* __restrict__ WdT)
{
    __shared__ float tile[32][33];
    const int bx = blockIdx.x;
    const int by = blockIdx.y;
    const int t  = threadIdx.x;
    const int lx = t & 31, ly = t >> 5;
#pragma unroll
    for (int r = 0; r < 32; r += 8)
        tile[ly + r][lx] = Wd[(size_t)(by * 32 + ly + r) * HID + bx * 32 + lx];
    __syncthreads();
#pragma unroll
    for (int r = 0; r < 32; r += 8)
        WdT[(size_t)(bx * 32 + ly + r) * IN_DIM + by * 32 + lx] = tile[lx][ly + r];
}

// ---------------------------------------------------------------------------
// Kernel 4: sparse decode  decoded[b,:] = sum_i val_i * WdT[idx_i,:] + b_dec
// ---------------------------------------------------------------------------
__global__ __launch_bounds__(256)
void decode_rows(const float* __restrict__ WdT, const float* __restrict__ bd,
                 const int* __restrict__ idxs, const float* __restrict__ vals,
                 float* __restrict__ out)
{
    const int row = blockIdx.x;
    const int d   = threadIdx.x * 4;
    float4 acc = *(const float4*)(bd + d);
    for (int i = 0; i < KSEL; ++i) {
        const int   j = idxs[row * KSEL + i];
        const float v = vals[row * KSEL + i];
        const float4 w = *(const float4*)(WdT + (size_t)j * IN_DIM + d);
        acc.x = fmaf(v, w.x, acc.x);
        acc.y = fmaf(v, w.y, acc.y);
        acc.z = fmaf(v, w.z, acc.z);
        acc.w = fmaf(v, w.w, acc.w);
    }
    *(float4*)(out + (size_t)row * IN_DIM + d) = acc;
}

__global__ __launch_bounds__(256)
void decode_rows_noT(const float* __restrict__ Wd, const float* __restrict__ bd,
                     const int* __restrict__ idxs, const float* __restrict__ vals,
                     float* __restrict__ out)
{
    const int row = blockIdx.x;
    const int d0  = threadIdx.x * 4;
    float acc[4];
#pragma unroll
    for (int q = 0; q < 4; ++q) acc[q] = bd[d0 + q];
    for (int i = 0; i < KSEL; ++i) {
        const int   j = idxs[row * KSEL + i];
        const float v = vals[row * KSEL + i];
#pragma unroll
        for (int q = 0; q < 4; ++q)
            acc[q] = fmaf(v, Wd[(size_t)(d0 + q) * HID + j], acc[q]);
    }
#pragma unroll
    for (int q = 0; q < 4; ++q) out[(size_t)row * IN_DIM + d0 + q] = acc[q];
}

// ---------------------------------------------------------------------------
extern "C" void kernel_launch(void* const* d_in, const int* in_sizes, int n_in,
                              void* d_out, int out_size, void* d_ws, size_t ws_size,
                              hipStream_t stream)
{
    const float* x     = (const float*)d_in[0];
    const float* W_enc = (const float*)d_in[1];
    const float* b_enc = (const float*)d_in[2];
    const float* W_dec = (const float*)d_in[3];
    const float* b_dec = (const float*)d_in[4];

    float* out     = (float*)d_out;
    float* sparse  = out;                                // [4096][16384]
    float* decoded = out + (size_t)BATCH * HID;          // [4096][1024]

    // ws layout: [idx list 512KB][val list 512KB][WdT 64MB]
    const size_t list_bytes = (size_t)BATCH * KSEL * 4;
    const size_t wdt_bytes  = (size_t)HID * IN_DIM * 4;
    int*   idx_l = (int*)d_ws;
    float* val_l = (float*)((char*)d_ws + list_bytes);
    float* WdT   = (float*)((char*)d_ws + 2 * list_bytes);
    const bool have_wdt = ws_size >= 2 * list_bytes + wdt_bytes;

    enc_gemm<<<dim3(HID / 128, BATCH / 128), 256, 0, stream>>>(x, W_enc, b_enc, sparse);

    topk_rows<<<BATCH, 256, 0, stream>>>(sparse, idx_l, val_l);

    if (have_wdt) {
        transpose_wdec<<<dim3(HID / 32, IN_DIM / 32), 256, 0, stream>>>(W_dec, WdT);
        decode_rows<<<BATCH, 256, 0, stream>>>(WdT, b_dec, idx_l, val_l, decoded);
    } else {
        decode_rows_noT<<<BATCH, 256, 0, stream>>>(W_dec, b_dec, idx_l, val_l, decoded);
    }
}

// Round 4
// 2068.798 us; speedup vs baseline: 2.4386x; 2.4386x over previous
//
#include <hip/hip_runtime.h>
#include <cstdint>
#include <cstddef>

#define BATCH   4096
#define IN_DIM  1024
#define HID     16384
#define KSEL    32

// ---------------------------------------------------------------------------
// Kernel 1: encoder GEMM  C[B,H] = X[B,D] @ W_enc[H,D]^T + b_enc
// fp32. 64x128 tile, BK=32, 512 threads (8 waves x 8 rows), lane owns 2 cols.
// A is WAVE-UNIFORM -> loaded via s_load_dwordx4 into SGPRs (scalar pipe);
// only B staged in LDS. v_fmac_f32 consumes the SGPR A operand directly.
//
// NUMERICS CONTRACT (do not change): per output element, fmaf over k in
// strictly ascending order with a single accumulator, then + bias. Top-k
// rank-32 boundary gaps are ~0.007; any reordering (MFMA bf16x3: absmax
// 4.31, or k-splitting) flips selections vs the np reference. MFMA unusable.
// This version only changes WHICH LANE computes which output; each output's
// k-chain (kq ascending, x->y->z->w within kq) is bit-identical.
//
// HISTORY:
//  r5 (16x8 micro-tile): acc[16][8]=128 regs spilled -> REGRESSED. Lesson:
//     accumulator must fit comfortably under the VGPR cap.
//  r6 (8x8, 4 blk/CU, A+B in LDS): 1830us. LDS-pipe-bound: per wave-kq,
//     16 ds_read_b128 (~192 LDS cyc) vs 512 VALU cyc; at 16 waves/CU LDS
//     demand = 1.5x VALU issue. FMA floor is 874us.
//  r7 (A from global, vector loads in loop): compiler hoisted 64 in-flight
//     global loads -> acc spilled to scratch (WRITE_SIZE 8.5GB vs 385MB!)
//     -> 5100us. Lesson: vector-loading A in the compute loop is unfixable;
//     the offload must not consume VGPRs at all.
//  r8 (this): A via SCALAR pipe. Wave-uniform rows -> s_load_dwordx4 to
//     SGPRs, issued as one volatile asm block per kq (8 loads + 1 wait) so
//     SGPR live range is bounded at 32 by construction and cannot be
//     hoisted across kq. LDS demand drops 8x (2 ds_read_b128 per 64 FMA
//     instrs); acc is 16 VGPRs -> cap 64 VGPR, 32 waves/CU.
//
// Staging (B only): global_load_lds width=16 into ROW-MAJOR LDS, 16B chunks
// XOR-swizzled by ((row>>3)&7). B-read rows {lane, lane+64} spread the 8
// chunk-slots evenly across lane>>3 groups -> conflict-free ds_read_b128.
// ---------------------------------------------------------------------------
#define BKK 32

typedef float f32x4_t __attribute__((ext_vector_type(4)));

__global__ __launch_bounds__(512, 8)
void enc_gemm(const float* __restrict__ X, const float* __restrict__ W,
              const float* __restrict__ bias, float* __restrict__ C)
{
    __shared__ __align__(16) float Bs[128 * BKK];   // 16 KB, row-major, swizzled

    const int bn = blockIdx.x;   // HID/128 = 128 (fast dim)
    const int bm = blockIdx.y;   // BATCH/64 = 64
    const int t  = threadIdx.x;  // 0..511
    const int lane = t & 63;
    const int wid  = t >> 6;     // 0..7: wave owns rows bm*64 + wid*8 .. +7

    float acc[8][2];
#pragma unroll
    for (int r = 0; r < 8; ++r) { acc[r][0] = 0.f; acc[r][1] = 0.f; }

    const float* Wb = W + (size_t)(bn * 128) * IN_DIM;

    // Wave-uniform A base (rows bm*64+wid*8 .. +7), forced to SGPR.
    const unsigned rowByte = (unsigned)__builtin_amdgcn_readfirstlane(
        (int)((unsigned)(bm * 64 + wid * 8) * (unsigned)(IN_DIM * 4)));
    const char* aBase = (const char*)X + rowByte;

    const int bswz = (lane >> 3) & 7;            // B-read swizzle key
    const float* bRow0 = Bs + (size_t)lane * BKK;        // col = lane
    const float* bRow1 = Bs + (size_t)(lane + 64) * BKK; // col = lane+64

    for (int k0 = 0; k0 < IN_DIM; k0 += BKK) {
        // ---- stage 128x32 B tile: 2 x 16B per thread (512 threads).
        // LDS slot s holds row m = s>>3, global 16B-chunk (s&7)^((m>>3)&7).
        // Lane-contiguous LDS dst satisfies wave-uniform-base + lane*16.
#pragma unroll
        for (int q = 0; q < 2; ++q) {
            const int s  = q * 512 + t;           // 0..1023
            const int m  = s >> 3;                // 0..127
            const int gc = (s & 7) ^ ((m >> 3) & 7);
            __builtin_amdgcn_global_load_lds(
                (const __attribute__((address_space(1))) void*)(Wb + (size_t)m * IN_DIM + k0 + gc * 4),
                (__attribute__((address_space(3))) void*)(Bs + s * 4), 16, 0, 0);
        }
        __syncthreads();   // drains vmcnt (global_load_lds) before reads

        // ---- compute: 8 groups of 4 consecutive k.
#pragma unroll
        for (int kq = 0; kq < 8; ++kq) {
            const float4 b0 = *(const float4*)(bRow0 + ((kq ^ bswz) * 4));
            const float4 b1 = *(const float4*)(bRow1 + ((kq ^ bswz) * 4));

            // A: 8 rows x 4 k into SGPRs. One volatile asm block per kq:
            // bounded SGPR live range (32), cannot be hoisted across kq
            // (volatile ordering), outputs ready at block end (wait inside).
            const char* apq = aBase + (size_t)(k0 + kq * 4) * 4;
            f32x4_t a0, a1, a2, a3, a4, a5, a6, a7;
            asm volatile(
                "s_load_dwordx4 %[r0], %[ap], 0x0\n\t"
                "s_load_dwordx4 %[r1], %[ap], 0x1000\n\t"
                "s_load_dwordx4 %[r2], %[ap], 0x2000\n\t"
                "s_load_dwordx4 %[r3], %[ap], 0x3000\n\t"
                "s_load_dwordx4 %[r4], %[ap], 0x4000\n\t"
                "s_load_dwordx4 %[r5], %[ap], 0x5000\n\t"
                "s_load_dwordx4 %[r6], %[ap], 0x6000\n\t"
                "s_load_dwordx4 %[r7], %[ap], 0x7000\n\t"
                "s_waitcnt lgkmcnt(0)"
                : [r0]"=s"(a0), [r1]"=s"(a1), [r2]"=s"(a2), [r3]"=s"(a3),
                  [r4]"=s"(a4), [r5]"=s"(a5), [r6]"=s"(a6), [r7]"=s"(a7)
                : [ap]"s"(apq));

            // k ascending per output: comp x,y,z,w (bit-identical chain).
            // v_fmac_f32 dst, sgpr, vgpr : one SGPR source is legal.
#define ROW_FMA(AV, R)                                   \
            acc[R][0] = fmaf(AV.x, b0.x, acc[R][0]);     \
            acc[R][1] = fmaf(AV.x, b1.x, acc[R][1]);     \
            acc[R][0] = fmaf(AV.y, b0.y, acc[R][0]);     \
            acc[R][1] = fmaf(AV.y, b1.y, acc[R][1]);     \
            acc[R][0] = fmaf(AV.z, b0.z, acc[R][0]);     \
            acc[R][1] = fmaf(AV.z, b1.z, acc[R][1]);     \
            acc[R][0] = fmaf(AV.w, b0.w, acc[R][0]);     \
            acc[R][1] = fmaf(AV.w, b1.w, acc[R][1]);
            ROW_FMA(a0, 0) ROW_FMA(a1, 1) ROW_FMA(a2, 2) ROW_FMA(a3, 3)
            ROW_FMA(a4, 4) ROW_FMA(a5, 5) ROW_FMA(a6, 6) ROW_FMA(a7, 7)
#undef ROW_FMA
        }
        __syncthreads();
    }

    const int r0 = bm * 64 + wid * 8;
    const int c0 = bn * 128 + lane;
    const float bv0 = bias[c0];
    const float bv1 = bias[c0 + 64];
#pragma unroll
    for (int r = 0; r < 8; ++r) {
        C[(size_t)(r0 + r) * HID + c0]      = acc[r][0] + bv0;
        C[(size_t)(r0 + r) * HID + c0 + 64] = acc[r][1] + bv1;
    }
}

// ---------------------------------------------------------------------------
// Kernel 2 (v4): per-row exact top-32 by |value|, 4-level radix select on
// abs bit pattern. Row cached in LDS (64 KB) -> global traffic = 1 read +
// 1 write. Suffix "scan" via wave shuffles (no LDS scan array / barriers).
// Levels: bits 30:23 (256), 22:15 (256), 14:7 (256), 6:0 (128).
// ---------------------------------------------------------------------------
__global__ __launch_bounds__(256)
void topk_rows(float* __restrict__ E, int* __restrict__ idx_out,
               float* __restrict__ val_out)
{
    const int row = blockIdx.x;
    float* p = E + (size_t)row * HID;
    const int t    = threadIdx.x;
    const int lane = t & 63;
    const int wid  = t >> 6;

    __shared__ __align__(16) float row_s[HID];   // 64 KB row cache
    __shared__ unsigned h8[8][257];              // lvl-0 privatized hists
    __shared__ unsigned hist[256];
    __shared__ unsigned wsum[4];
    __shared__ unsigned s_prefix;
    __shared__ int s_rank, s_eq, s_cnt;

    // async-load the whole row into LDS (lane-contiguous 16B chunks)
#pragma unroll
    for (int c = 0; c < 16; ++c) {
        const int s = c * 256 + t;
        __builtin_amdgcn_global_load_lds(
            (const __attribute__((address_space(1))) void*)(p + (size_t)s * 4),
            (__attribute__((address_space(3))) void*)(row_s + s * 4), 16, 0, 0);
    }
    for (int i = t; i < 8 * 257; i += 256) ((unsigned*)h8)[i] = 0u;
    if (t == 0) { s_rank = KSEL; s_prefix = 0u; s_eq = 0; s_cnt = 0; }
    __syncthreads();

    // ---- level 0: exponent-byte histogram into 8 privatized copies
    unsigned* myh = h8[t & 7];
#pragma unroll
    for (int c = 0; c < 16; ++c) {
        const float4 v = *(const float4*)(row_s + (c * 256 + t) * 4);
        const float vv[4] = {v.x, v.y, v.z, v.w};
#pragma unroll
        for (int j = 0; j < 4; ++j)
            atomicAdd(&myh[(__float_as_uint(vv[j]) & 0x7FFFFFFFu) >> 23], 1u);
    }
    __syncthreads();

    const int psh_arr[4]  = {31, 23, 15, 7};
    const int sh_arr[4]   = {23, 15, 7, 0};
    const unsigned msk[4] = {255u, 255u, 255u, 127u};
    const int bits_arr[4] = {8, 8, 8, 7};

#pragma unroll
    for (int lvl = 0; lvl < 4; ++lvl) {
        const int r = s_rank;
        const unsigned pfx = s_prefix;

        unsigned mycnt;
        if (lvl == 0) {
            unsigned m = 0;
#pragma unroll
            for (int c = 0; c < 8; ++c) m += h8[c][t];
            mycnt = m;                       // own bin, no barrier needed
        } else {
            hist[t] = 0u;
            __syncthreads();
            const int psh = psh_arr[lvl];
            const int sh  = sh_arr[lvl];
#pragma unroll
            for (int c = 0; c < 16; ++c) {
                const float4 v = *(const float4*)(row_s + (c * 256 + t) * 4);
                const float vv[4] = {v.x, v.y, v.z, v.w};
#pragma unroll
                for (int j = 0; j < 4; ++j) {
                    const unsigned k = __float_as_uint(vv[j]) & 0x7FFFFFFFu;
                    if ((k >> psh) == pfx)   // few matches: contention trivial
                        atomicAdd(&hist[(k >> sh) & msk[lvl]], 1u);
                }
            }
            __syncthreads();
            mycnt = hist[t];
        }

        // wave-level inclusive suffix scan of bin counts (bin index = t)
        unsigned sv = mycnt;
#pragma unroll
        for (int off = 1; off < 64; off <<= 1) {
            const unsigned u = __shfl_down(sv, off, 64);
            sv += (lane + off < 64) ? u : 0u;
        }
        if (lane == 0) wsum[wid] = sv;       // this wave's 64-bin total
        __syncthreads();
        unsigned above = 0;
        for (int ww = wid + 1; ww < 4; ++ww) above += wsum[ww];
        const unsigned suff  = sv + above;   // sum of bins >= t
        const unsigned suffn = suff - mycnt; // sum of bins >  t
        if (suff >= (unsigned)r && suffn < (unsigned)r) {  // exactly one thread
            s_rank   = r - (int)suffn;
            s_prefix = (pfx << bits_arr[lvl]) | (unsigned)t;
        }
        __syncthreads();
    }

    const unsigned vkey = s_prefix;   // exact 31-bit abs key of the 32nd largest
    const int eq_need   = s_rank;     // how many ==vkey elements to keep (>=1)

    // ---- final: mask from LDS, write global row + compact (idx,val) lists
#pragma unroll
    for (int c = 0; c < 16; ++c) {
        const int i0 = (c * 256 + t) * 4;
        const float4 v = *(const float4*)(row_s + i0);
        float vv[4] = {v.x, v.y, v.z, v.w};
#pragma unroll
        for (int j = 0; j < 4; ++j) {
            const unsigned k = __float_as_uint(vv[j]) & 0x7FFFFFFFu;
            bool keep = false;
            if (k > vkey) keep = true;
            else if (k == vkey) {
                const int slot = atomicAdd(&s_eq, 1);
                if (slot < eq_need) keep = true;
            }
            if (keep) {
                const int ls = atomicAdd(&s_cnt, 1);
                idx_out[row * KSEL + ls] = i0 + j;
                val_out[row * KSEL + ls] = vv[j];
            } else {
                vv[j] = 0.f;
            }
        }
        float4 o; o.x = vv[0]; o.y = vv[1]; o.z = vv[2]; o.w = vv[3];
        *(float4*)(p + i0) = o;
    }
}

// ---------------------------------------------------------------------------
// Kernel 3: transpose W_dec [1024,16384] -> WdT [16384,1024] (ws scratch)
// ---------------------------------------------------------------------------
__global__ __launch_bounds__(256)
void transpose_wdec(const float* __restrict__ Wd, float* __restrict__ WdT)
{
    __shared__ float tile[32][33];
    const int bx = blockIdx.x;
    const int by = blockIdx.y;
    const int t  = threadIdx.x;
    const int lx = t & 31, ly = t >> 5;
#pragma unroll
    for (int r = 0; r < 32; r += 8)
        tile[ly + r][lx] = Wd[(size_t)(by * 32 + ly + r) * HID + bx * 32 + lx];
    __syncthreads();
#pragma unroll
    for (int r = 0; r < 32; r += 8)
        WdT[(size_t)(bx * 32 + ly + r) * IN_DIM + by * 32 + lx] = tile[lx][ly + r];
}

// ---------------------------------------------------------------------------
// Kernel 4: sparse decode  decoded[b,:] = sum_i val_i * WdT[idx_i,:] + b_dec
// ---------------------------------------------------------------------------
__global__ __launch_bounds__(256)
void decode_rows(const float* __restrict__ WdT, const float* __restrict__ bd,
                 const int* __restrict__ idxs, const float* __restrict__ vals,
                 float* __restrict__ out)
{
    const int row = blockIdx.x;
    const int d   = threadIdx.x * 4;
    float4 acc = *(const float4*)(bd + d);
    for (int i = 0; i < KSEL; ++i) {
        const int   j = idxs[row * KSEL + i];
        const float v = vals[row * KSEL + i];
        const float4 w = *(const float4*)(WdT + (size_t)j * IN_DIM + d);
        acc.x = fmaf(v, w.x, acc.x);
        acc.y = fmaf(v, w.y, acc.y);
        acc.z = fmaf(v, w.z, acc.z);
        acc.w = fmaf(v, w.w, acc.w);
    }
    *(float4*)(out + (size_t)row * IN_DIM + d) = acc;
}

__global__ __launch_bounds__(256)
void decode_rows_noT(const float* __restrict__ Wd, const float* __restrict__ bd,
                     const int* __restrict__ idxs, const float* __restrict__ vals,
                     float* __restrict__ out)
{
    const int row = blockIdx.x;
    const int d0  = threadIdx.x * 4;
    float acc[4];
#pragma unroll
    for (int q = 0; q < 4; ++q) acc[q] = bd[d0 + q];
    for (int i = 0; i < KSEL; ++i) {
        const int   j = idxs[row * KSEL + i];
        const float v = vals[row * KSEL + i];
#pragma unroll
        for (int q = 0; q < 4; ++q)
            acc[q] = fmaf(v, Wd[(size_t)(d0 + q) * HID + j], acc[q]);
    }
#pragma unroll
    for (int q = 0; q < 4; ++q) out[(size_t)row * IN_DIM + d0 + q] = acc[q];
}

// ---------------------------------------------------------------------------
extern "C" void kernel_launch(void* const* d_in, const int* in_sizes, int n_in,
                              void* d_out, int out_size, void* d_ws, size_t ws_size,
                              hipStream_t stream)
{
    const float* x     = (const float*)d_in[0];
    const float* W_enc = (const float*)d_in[1];
    const float* b_enc = (const float*)d_in[2];
    const float* W_dec = (const float*)d_in[3];
    const float* b_dec = (const float*)d_in[4];

    float* out     = (float*)d_out;
    float* sparse  = out;                                // [4096][16384]
    float* decoded = out + (size_t)BATCH * HID;          // [4096][1024]

    // ws layout: [idx list 512KB][val list 512KB][WdT 64MB]
    const size_t list_bytes = (size_t)BATCH * KSEL * 4;
    const size_t wdt_bytes  = (size_t)HID * IN_DIM * 4;
    int*   idx_l = (int*)d_ws;
    float* val_l = (float*)((char*)d_ws + list_bytes);
    float* WdT   = (float*)((char*)d_ws + 2 * list_bytes);
    const bool have_wdt = ws_size >= 2 * list_bytes + wdt_bytes;

    enc_gemm<<<dim3(HID / 128, BATCH / 64), 512, 0, stream>>>(x, W_enc, b_enc, sparse);

    topk_rows<<<BATCH, 256, 0, stream>>>(sparse, idx_l, val_l);

    if (have_wdt) {
        transpose_wdec<<<dim3(HID / 32, IN_DIM / 32), 256, 0, stream>>>(W_dec, WdT);
        decode_rows<<<BATCH, 256, 0, stream>>>(WdT, b_dec, idx_l, val_l, decoded);
    } else {
        decode_rows_noT<<<BATCH, 256, 0, stream>>>(W_dec, b_dec, idx_l, val_l, decoded);
    }
}

// Round 8
// 2037.068 us; speedup vs baseline: 2.4766x; 1.0156x over previous
//
#include <hip/hip_runtime.h>
#include <cstdint>
#include <cstddef>

#define BATCH   4096
#define IN_DIM  1024
#define HID     16384
#define KSEL    32

// ---------------------------------------------------------------------------
// Kernel 1: encoder GEMM  C[B,H] = X[B,D] @ W_enc[H,D]^T + b_enc
// fp32. 64x128 tile, BK=32, 512 threads (8 waves x 8 rows), lane owns 2 cols.
// A is WAVE-UNIFORM -> s_load_dwordx4 into SGPRs (scalar pipe); only B in
// LDS. FMAs in plain C (fmaf) — FMA inline-asm is BANNED (see r9/r10).
//
// NUMERICS CONTRACT (do not change): per output element, fmaf over k in
// strictly ascending order with a single accumulator, then + bias. Top-k
// rank-32 boundary gaps are ~0.007; any reordering (MFMA bf16x3: absmax
// 4.31, or k-splitting) flips selections vs the np reference. MFMA unusable.
//
// HISTORY:
//  r5: 16x8 micro-tile spilled acc -> REGRESSED (1850->2600).
//  r6: 8x8, 4 blk/CU, A+B in LDS: 1830us, LDS-pipe-bound (1.0 B/FMA).
//  r7: A via vector global loads: compiler hoisted 64 loads, acc spilled,
//      WRITE_SIZE 8.5GB, 5100us. Vector-loading A in-loop is unfixable.
//  r8: A via SCALAR pipe (s_load_dwordx4, volatile asm per kq): 1650us.
//      WRITE_SIZE exactly 256MiB (no spill), occ 87%, VALUBusy 79%.
//      Remaining: 1.34e8 bank-conflict cyc (13%) + ~1M cyc/CU s->v movs.
//  r9/r10: swizzle fix + FMA inline asm (VOP2 fmac, then VOP3 fma):
//      BOTH ABORTED (core dump) with identical signatures. Encoding theory
//      dead; FMA-asm path toxic by elimination (swizzle change is value-
//      preserving and in-bounds). DO NOT hand-emit FMA asm in this kernel.
//  r11: r8 + swizzle fix ONLY, FMAs in plain C — never ran (container
//      failed twice, infra). THIS ROUND: identical resubmit. If it core-
//      dumps with the pytest signature, suspect the s_load asm block and
//      drop all inline asm next.
//
//  Swizzle fix rationale (from r8 counters, 1.342e8 conflict cyc):
//      B rows are lane*128B apart -> every row starts at bank 0; r8's key
//      (row>>3)&7 is constant within each 8-lane group -> 8 lanes pile on
//      one 4-bank group. New key row&7 varies within the group -> lanes
//      0..7 read 8 distinct 16B chunk slots -> all 32 banks covered ->
//      conflict-free. Staging gc changed to match (both-sides-or-neither);
//      per 8-lane group the staged 128B of global is the same bytes in a
//      permuted chunk order -> still one coalesced 128B segment.
// ---------------------------------------------------------------------------
#define BKK 32

typedef float f32x4_t __attribute__((ext_vector_type(4)));

__global__ __launch_bounds__(512, 8)
void enc_gemm(const float* __restrict__ X, const float* __restrict__ W,
              const float* __restrict__ bias, float* __restrict__ C)
{
    __shared__ __align__(16) float Bs[128 * BKK];   // 16 KB, row-major, swizzled

    const int bn = blockIdx.x;   // HID/128 = 128 (fast dim)
    const int bm = blockIdx.y;   // BATCH/64 = 64
    const int t  = threadIdx.x;  // 0..511
    const int lane = t & 63;
    const int wid  = t >> 6;     // 0..7: wave owns rows bm*64 + wid*8 .. +7

    float acc[8][2];
#pragma unroll
    for (int r = 0; r < 8; ++r) { acc[r][0] = 0.f; acc[r][1] = 0.f; }

    const float* Wb = W + (size_t)(bn * 128) * IN_DIM;

    // Wave-uniform A base (rows bm*64+wid*8 .. +7), forced to SGPR.
    const unsigned rowByte = (unsigned)__builtin_amdgcn_readfirstlane(
        (int)((unsigned)(bm * 64 + wid * 8) * (unsigned)(IN_DIM * 4)));
    const char* aBase = (const char*)X + rowByte;

    const int bswz = lane & 7;   // B-read swizzle key (row&7; (lane+64)&7 same)
    const float* bRow0 = Bs + (size_t)lane * BKK;        // col = lane
    const float* bRow1 = Bs + (size_t)(lane + 64) * BKK; // col = lane+64

    for (int k0 = 0; k0 < IN_DIM; k0 += BKK) {
        // ---- stage 128x32 B tile: 2 x 16B per thread (512 threads).
        // LDS slot s (16B) holds row m = s>>3, global chunk (s&7)^(m&7).
        // Read of logical chunk kq of row m is at physical chunk kq^(m&7):
        // lanes 0..7 read 8 distinct chunks -> all 32 banks, conflict-free.
        // Lane-contiguous LDS dst satisfies wave-uniform-base + lane*16;
        // each 8-lane group still reads one contiguous (permuted) 128B of
        // global -> fully coalesced.
#pragma unroll
        for (int q = 0; q < 2; ++q) {
            const int s  = q * 512 + t;           // 0..1023
            const int m  = s >> 3;                // 0..127
            const int gc = (s & 7) ^ (m & 7);
            __builtin_amdgcn_global_load_lds(
                (const __attribute__((address_space(1))) void*)(Wb + (size_t)m * IN_DIM + k0 + gc * 4),
                (__attribute__((address_space(3))) void*)(Bs + s * 4), 16, 0, 0);
        }
        __syncthreads();   // drains vmcnt (global_load_lds) before reads

        // ---- compute: 8 groups of 4 consecutive k.
#pragma unroll
        for (int kq = 0; kq < 8; ++kq) {
            const float4 b0 = *(const float4*)(bRow0 + ((kq ^ bswz) * 4));
            const float4 b1 = *(const float4*)(bRow1 + ((kq ^ bswz) * 4));

            // A: 8 rows x 4 k into SGPRs. One volatile asm block per kq:
            // bounded SGPR live range (32), cannot be hoisted across kq.
            const char* apq = aBase + (size_t)(k0 + kq * 4) * 4;
            f32x4_t a0, a1, a2, a3, a4, a5, a6, a7;
            asm volatile(
                "s_load_dwordx4 %[r0], %[ap], 0x0\n\t"
                "s_load_dwordx4 %[r1], %[ap], 0x1000\n\t"
                "s_load_dwordx4 %[r2], %[ap], 0x2000\n\t"
                "s_load_dwordx4 %[r3], %[ap], 0x3000\n\t"
                "s_load_dwordx4 %[r4], %[ap], 0x4000\n\t"
                "s_load_dwordx4 %[r5], %[ap], 0x5000\n\t"
                "s_load_dwordx4 %[r6], %[ap], 0x6000\n\t"
                "s_load_dwordx4 %[r7], %[ap], 0x7000\n\t"
                "s_waitcnt lgkmcnt(0)"
                : [r0]"=s"(a0), [r1]"=s"(a1), [r2]"=s"(a2), [r3]"=s"(a3),
                  [r4]"=s"(a4), [r5]"=s"(a5), [r6]"=s"(a6), [r7]"=s"(a7)
                : [ap]"s"(apq));

            // k ascending per output, x->y->z->w: bit-identical chain.
            // Plain fmaf (NO inline asm here — r9/r10 lesson).
#define ROW_FMA(AV, R)                                   \
            acc[R][0] = fmaf(AV.x, b0.x, acc[R][0]);     \
            acc[R][1] = fmaf(AV.x, b1.x, acc[R][1]);     \
            acc[R][0] = fmaf(AV.y, b0.y, acc[R][0]);     \
            acc[R][1] = fmaf(AV.y, b1.y, acc[R][1]);     \
            acc[R][0] = fmaf(AV.z, b0.z, acc[R][0]);     \
            acc[R][1] = fmaf(AV.z, b1.z, acc[R][1]);     \
            acc[R][0] = fmaf(AV.w, b0.w, acc[R][0]);     \
            acc[R][1] = fmaf(AV.w, b1.w, acc[R][1]);
            ROW_FMA(a0, 0) ROW_FMA(a1, 1) ROW_FMA(a2, 2) ROW_FMA(a3, 3)
            ROW_FMA(a4, 4) ROW_FMA(a5, 5) ROW_FMA(a6, 6) ROW_FMA(a7, 7)
#undef ROW_FMA
        }
        __syncthreads();
    }

    const int r0 = bm * 64 + wid * 8;
    const int c0 = bn * 128 + lane;
    const float bv0 = bias[c0];
    const float bv1 = bias[c0 + 64];
#pragma unroll
    for (int r = 0; r < 8; ++r) {
        C[(size_t)(r0 + r) * HID + c0]      = acc[r][0] + bv0;
        C[(size_t)(r0 + r) * HID + c0 + 64] = acc[r][1] + bv1;
    }
}

// ---------------------------------------------------------------------------
// Kernel 2 (v4): per-row exact top-32 by |value|, 4-level radix select on
// abs bit pattern. Row cached in LDS (64 KB) -> global traffic = 1 read +
// 1 write. Suffix "scan" via wave shuffles (no LDS scan array / barriers).
// Levels: bits 30:23 (256), 22:15 (256), 14:7 (256), 6:0 (128).
// ---------------------------------------------------------------------------
__global__ __launch_bounds__(256)
void topk_rows(float* __restrict__ E, int* __restrict__ idx_out,
               float* __restrict__ val_out)
{
    const int row = blockIdx.x;
    float* p = E + (size_t)row * HID;
    const int t    = threadIdx.x;
    const int lane = t & 63;
    const int wid  = t >> 6;

    __shared__ __align__(16) float row_s[HID];   // 64 KB row cache
    __shared__ unsigned h8[8][257];              // lvl-0 privatized hists
    __shared__ unsigned hist[256];
    __shared__ unsigned wsum[4];
    __shared__ unsigned s_prefix;
    __shared__ int s_rank, s_eq, s_cnt;

    // async-load the whole row into LDS (lane-contiguous 16B chunks)
#pragma unroll
    for (int c = 0; c < 16; ++c) {
        const int s = c * 256 + t;
        __builtin_amdgcn_global_load_lds(
            (const __attribute__((address_space(1))) void*)(p + (size_t)s * 4),
            (__attribute__((address_space(3))) void*)(row_s + s * 4), 16, 0, 0);
    }
    for (int i = t; i < 8 * 257; i += 256) ((unsigned*)h8)[i] = 0u;
    if (t == 0) { s_rank = KSEL; s_prefix = 0u; s_eq = 0; s_cnt = 0; }
    __syncthreads();

    // ---- level 0: exponent-byte histogram into 8 privatized copies
    unsigned* myh = h8[t & 7];
#pragma unroll
    for (int c = 0; c < 16; ++c) {
        const float4 v = *(const float4*)(row_s + (c * 256 + t) * 4);
        const float vv[4] = {v.x, v.y, v.z, v.w};
#pragma unroll
        for (int j = 0; j < 4; ++j)
            atomicAdd(&myh[(__float_as_uint(vv[j]) & 0x7FFFFFFFu) >> 23], 1u);
    }
    __syncthreads();

    const int psh_arr[4]  = {31, 23, 15, 7};
    const int sh_arr[4]   = {23, 15, 7, 0};
    const unsigned msk[4] = {255u, 255u, 255u, 127u};
    const int bits_arr[4] = {8, 8, 8, 7};

#pragma unroll
    for (int lvl = 0; lvl < 4; ++lvl) {
        const int r = s_rank;
        const unsigned pfx = s_prefix;

        unsigned mycnt;
        if (lvl == 0) {
            unsigned m = 0;
#pragma unroll
            for (int c = 0; c < 8; ++c) m += h8[c][t];
            mycnt = m;                       // own bin, no barrier needed
        } else {
            hist[t] = 0u;
            __syncthreads();
            const int psh = psh_arr[lvl];
            const int sh  = sh_arr[lvl];
#pragma unroll
            for (int c = 0; c < 16; ++c) {
                const float4 v = *(const float4*)(row_s + (c * 256 + t) * 4);
                const float vv[4] = {v.x, v.y, v.z, v.w};
#pragma unroll
                for (int j = 0; j < 4; ++j) {
                    const unsigned k = __float_as_uint(vv[j]) & 0x7FFFFFFFu;
                    if ((k >> psh) == pfx)   // few matches: contention trivial
                        atomicAdd(&hist[(k >> sh) & msk[lvl]], 1u);
                }
            }
            __syncthreads();
            mycnt = hist[t];
        }

        // wave-level inclusive suffix scan of bin counts (bin index = t)
        unsigned sv = mycnt;
#pragma unroll
        for (int off = 1; off < 64; off <<= 1) {
            const unsigned u = __shfl_down(sv, off, 64);
            sv += (lane + off < 64) ? u : 0u;
        }
        if (lane == 0) wsum[wid] = sv;       // this wave's 64-bin total
        __syncthreads();
        unsigned above = 0;
        for (int ww = wid + 1; ww < 4; ++ww) above += wsum[ww];
        const unsigned suff  = sv + above;   // sum of bins >= t
        const unsigned suffn = suff - mycnt; // sum of bins >  t
        if (suff >= (unsigned)r && suffn < (unsigned)r) {  // exactly one thread
            s_rank   = r - (int)suffn;
            s_prefix = (pfx << bits_arr[lvl]) | (unsigned)t;
        }
        __syncthreads();
    }

    const unsigned vkey = s_prefix;   // exact 31-bit abs key of the 32nd largest
    const int eq_need   = s_rank;     // how many ==vkey elements to keep (>=1)

    // ---- final: mask from LDS, write global row + compact (idx,val) lists
#pragma unroll
    for (int c = 0; c < 16; ++c) {
        const int i0 = (c * 256 + t) * 4;
        const float4 v = *(const float4*)(row_s + i0);
        float vv[4] = {v.x, v.y, v.z, v.w};
#pragma unroll
        for (int j = 0; j < 4; ++j) {
            const unsigned k = __float_as_uint(vv[j]) & 0x7FFFFFFFu;
            bool keep = false;
            if (k > vkey) keep = true;
            else if (k == vkey) {
                const int slot = atomicAdd(&s_eq, 1);
                if (slot < eq_need) keep = true;
            }
            if (keep) {
                const int ls = atomicAdd(&s_cnt, 1);
                idx_out[row * KSEL + ls] = i0 + j;
                val_out[row * KSEL + ls] = vv[j];
            } else {
                vv[j] = 0.f;
            }
        }
        float4 o; o.x = vv[0]; o.y = vv[1]; o.z = vv[2]; o.w = vv[3];
        *(float4*)(p + i0) = o;
    }
}

// ---------------------------------------------------------------------------
// Kernel 3: transpose W_dec [1024,16384] -> WdT [16384,1024] (ws scratch)
// ---------------------------------------------------------------------------
__global__ __launch_bounds__(256)
void transpose_wdec(const float* __restrict__ Wd, float* __restrict__ WdT)
{
    __shared__ float tile[32][33];
    const int bx = blockIdx.x;
    const int by = blockIdx.y;
    const int t  = threadIdx.x;
    const int lx = t & 31, ly = t >> 5;
#pragma unroll
    for (int r = 0; r < 32; r += 8)
        tile[ly + r][lx] = Wd[(size_t)(by * 32 + ly + r) * HID + bx * 32 + lx];
    __syncthreads();
#pragma unroll
    for (int r = 0; r < 32; r += 8)
        WdT[(size_t)(bx * 32 + ly + r) * IN_DIM + by * 32 + lx] = tile[lx][ly + r];
}

// ---------------------------------------------------------------------------
// Kernel 4: sparse decode  decoded[b,:] = sum_i val_i * WdT[idx_i,:] + b_dec
// ---------------------------------------------------------------------------
__global__ __launch_bounds__(256)
void decode_rows(const float* __restrict__ WdT, const float* __restrict__ bd,
                 const int* __restrict__ idxs, const float* __restrict__ vals,
                 float* __restrict__ out)
{
    const int row = blockIdx.x;
    const int d   = threadIdx.x * 4;
    float4 acc = *(const float4*)(bd + d);
    for (int i = 0; i < KSEL; ++i) {
        const int   j = idxs[row * KSEL + i];
        const float v = vals[row * KSEL + i];
        const float4 w = *(const float4*)(WdT + (size_t)j * IN_DIM + d);
        acc.x = fmaf(v, w.x, acc.x);
        acc.y = fmaf(v, w.y, acc.y);
        acc.z = fmaf(v, w.z, acc.z);
        acc.w = fmaf(v, w.w, acc.w);
    }
    *(float4*)(out + (size_t)row * IN_DIM + d) = acc;
}

__global__ __launch_bounds__(256)
void decode_rows_noT(const float* __restrict__ Wd, const float* __restrict__ bd,
                     const int* __restrict__ idxs, const float* __restrict__ vals,
                     float* __restrict__ out)
{
    const int row = blockIdx.x;
    const int d0  = threadIdx.x * 4;
    float acc[4];
#pragma unroll
    for (int q = 0; q < 4; ++q) acc[q] = bd[d0 + q];
    for (int i = 0; i < KSEL; ++i) {
        const int   j = idxs[row * KSEL + i];
        const float v = vals[row * KSEL + i];
#pragma unroll
        for (int q = 0; q < 4; ++q)
            acc[q] = fmaf(v, Wd[(size_t)(d0 + q) * HID + j], acc[q]);
    }
#pragma unroll
    for (int q = 0; q < 4; ++q) out[(size_t)row * IN_DIM + d0 + q] = acc[q];
}

// ---------------------------------------------------------------------------
extern "C" void kernel_launch(void* const* d_in, const int* in_sizes, int n_in,
                              void* d_out, int out_size, void* d_ws, size_t ws_size,
                              hipStream_t stream)
{
    const float* x     = (const float*)d_in[0];
    const float* W_enc = (const float*)d_in[1];
    const float* b_enc = (const float*)d_in[2];
    const float* W_dec = (const float*)d_in[3];
    const float* b_dec = (const float*)d_in[4];

    float* out     = (float*)d_out;
    float* sparse  = out;                                // [4096][16384]
    float* decoded = out + (size_t)BATCH * HID;          // [4096][1024]

    // ws layout: [idx list 512KB][val list 512KB][WdT 64MB]
    const size_t list_bytes = (size_t)BATCH * KSEL * 4;
    const size_t wdt_bytes  = (size_t)HID * IN_DIM * 4;
    int*   idx_l = (int*)d_ws;
    float* val_l = (float*)((char*)d_ws + list_bytes);
    float* WdT   = (float*)((char*)d_ws + 2 * list_bytes);
    const bool have_wdt = ws_size >= 2 * list_bytes + wdt_bytes;

    enc_gemm<<<dim3(HID / 128, BATCH / 64), 512, 0, stream>>>(x, W_enc, b_enc, sparse);

    topk_rows<<<BATCH, 256, 0, stream>>>(sparse, idx_l, val_l);

    if (have_wdt) {
        transpose_wdec<<<dim3(HID / 32, IN_DIM / 32), 256, 0, stream>>>(W_dec, WdT);
        decode_rows<<<BATCH, 256, 0, stream>>>(WdT, b_dec, idx_l, val_l, decoded);
    } else {
        decode_rows_noT<<<BATCH, 256, 0, stream>>>(W_dec, b_dec, idx_l, val_l, decoded);
    }
}